// Round 14
// baseline (119.527 us; speedup 1.0000x reference)
//
#include <hip/hip_runtime.h>

// Problem constants
#define B_     64
#define L_     1024
#define D_     1280   // 320 float4
#define H1_    640
#define H2_    320
#define NSPLIT 32     // per-batch even-split stripes for pooling
#define KS_    16     // k-splits for mlp1
#define KC_    80     // 1280/16
#define NJT_   10     // W1 j-tiles of 64
#define NJT2_  5      // W2 j-tiles of 64

// ---------------- Kernel 1: stripe partials + counter init ----------------
// grid (NSPLIT, B_) x 320 thr. Stripe work BYTE-IDENTICAL to R7-R13 (probe:
// 25.5us, HBM ceiling). s==0 blocks init ctr1[jt] (for mlp1h) and ctr2[b]
// (for mlp2y) — consumed 1-2 kernel launches later; kernel-boundary visibility
// + per-replay re-init (R13-validated pattern).
__global__ void pool_partial(const float* __restrict__ rep, const int* __restrict__ blen,
                             float* __restrict__ part, unsigned int* __restrict__ ctr1,
                             unsigned int* __restrict__ ctr2) {
    const int s   = blockIdx.x;     // stripe
    const int b   = blockIdx.y;     // batch
    const int tid = threadIdx.x;    // 0..319 (float4 lane)

    if (s == 0 && tid == 0) {
        ctr2[b] = 0u;
        if (b < NJT_) ctr1[b] = 0u;
    }

    const int n  = blen[b] - 2;     // valid rows (>=1)
    const int l0 = 1 + (s * n) / NSPLIT;
    const int l1 = 1 + ((s + 1) * n) / NSPLIT;

    float4 acc = make_float4(0.f, 0.f, 0.f, 0.f);
    const float4* base = (const float4*)rep + (size_t)b * L_ * (D_ / 4) + tid;
    #pragma unroll 8
    for (int l = l0; l < l1; ++l) {
        float4 v = base[(size_t)l * (D_ / 4)];
        acc.x += v.x; acc.y += v.y; acc.z += v.z; acc.w += v.w;
    }
    ((float4*)part)[((size_t)b * NSPLIT + s) * (D_ / 4) + tid] = acc;
}

// ---------------- Kernel 2: stripe reduce -> pooled (R11-proven) ----------------
// grid (5, B_) = 320 blocks x 64 thr.
__global__ void pool_reduce(const float* __restrict__ part, const int* __restrict__ blen,
                            float* __restrict__ pooled) {
    const int qt  = blockIdx.x;     // col quarter-tile 0..4
    const int b   = blockIdx.y;     // batch
    const int tid = threadIdx.x;    // 0..63
    const int col = qt * 64 + tid;  // float4 column 0..319

    int n = blen[b] - 2; if (n < 1) n = 1;
    const float inv = 1.0f / (float)n;
    const float4* p = (const float4*)part + (size_t)b * NSPLIT * (D_ / 4) + col;
    float4 a = make_float4(0.f, 0.f, 0.f, 0.f);
    #pragma unroll
    for (int s = 0; s < NSPLIT; ++s) {
        float4 v = p[(size_t)s * (D_ / 4)];
        a.x += v.x; a.y += v.y; a.z += v.z; a.w += v.w;
    }
    ((float4*)pooled)[(size_t)b * (D_ / 4) + col] =
        make_float4(a.x * inv, a.y * inv, a.z * inv, a.w * inv);
}

// ---------------- Kernel 3: mlp1 partials + last-ks-arrival h finalize ------------
// grid (NJT_, KS_) = 160 blocks x 512 thr. W1 read ONCE grid-wide (R11-proven
// compute). The 16th-arriving ks-block for tile jt (ctr1[jt] init 0 -> exact)
// reduces hpart over ks, +b1, relu -> hrow[b][j]. Fence+atomic cross-block
// pattern validated in R13.
__global__ void mlp1h(const float* __restrict__ pooled, const float* __restrict__ W1,
                      const float* __restrict__ b1, float* __restrict__ hpart,
                      float* __restrict__ hrow, unsigned int* __restrict__ ctr1) {
    const int jt  = blockIdx.x;     // 0..9
    const int ks  = blockIdx.y;     // 0..15
    const int tid = threadIdx.x;    // 0..511
    const int jl  = tid & 63;
    const int b0  = (tid >> 6) * 8;
    const int k0  = ks * KC_;
    const int j0  = jt * 64;

    __shared__ float pl[B_][KC_];   // pooled k-slice (20 KB)
    for (int e = tid; e < B_ * (KC_ / 4); e += 512) {
        const int b   = e / (KC_ / 4);
        const int kk4 = e % (KC_ / 4);
        float4 v = ((const float4*)pooled)[(size_t)b * (D_ / 4) + (k0 / 4) + kk4];
        *(float4*)&pl[b][kk4 * 4] = v;
    }
    __syncthreads();

    float acc[8];
    #pragma unroll
    for (int r = 0; r < 8; ++r) acc[r] = 0.f;

    const float* w1p = W1 + (size_t)k0 * H1_ + j0 + jl;
    for (int kk = 0; kk < KC_; kk += 4) {
        const float w0 = w1p[(size_t)(kk + 0) * H1_];
        const float w1 = w1p[(size_t)(kk + 1) * H1_];
        const float w2 = w1p[(size_t)(kk + 2) * H1_];
        const float w3 = w1p[(size_t)(kk + 3) * H1_];
        #pragma unroll
        for (int r = 0; r < 8; ++r) {
            float4 pv = *(const float4*)&pl[b0 + r][kk];
            acc[r] = fmaf(pv.x, w0, acc[r]);
            acc[r] = fmaf(pv.y, w1, acc[r]);
            acc[r] = fmaf(pv.z, w2, acc[r]);
            acc[r] = fmaf(pv.w, w3, acc[r]);
        }
    }
    float* hp = hpart + (size_t)ks * B_ * H1_;
    #pragma unroll
    for (int r = 0; r < 8; ++r)
        hp[(size_t)(b0 + r) * H1_ + j0 + jl] = acc[r];

    // ---- last-arrival finalize for this jt ----
    __threadfence();                   // release my hpart writes
    __syncthreads();
    __shared__ unsigned int lastf;
    if (tid == 0) {
        unsigned int old = atomicAdd(&ctr1[jt], 1u);
        lastf = (old == (unsigned)(KS_ - 1)) ? 1u : 0u;   // init==0 -> exact
    }
    __syncthreads();

    if (lastf) {
        __threadfence();               // acquire sibling blocks' hpart writes
        const float bias = b1[j0 + jl];
        #pragma unroll
        for (int r = 0; r < 8; ++r) {
            const int b = b0 + r;
            float s = bias;
            #pragma unroll
            for (int k2 = 0; k2 < KS_; ++k2)
                s += hpart[((size_t)k2 * B_ + b) * H1_ + j0 + jl];
            hrow[(size_t)b * H1_ + j0 + jl] = fmaxf(s, 0.f);
        }
    }
}

// ---------------- Kernel 4: emb from hrow + last-block y (R13-proven) ------------
// grid (NJT2_, B_) = 320 blocks x 512 thr. hrow is dense & final (kernel
// boundary), so no hpart reduce here. ctr2 init 0 -> exact last detection.
__global__ void mlp2y(const float* __restrict__ hrow, const float* __restrict__ W2,
                      const float* __restrict__ b2, const float* __restrict__ W3,
                      const float* __restrict__ b3, float* __restrict__ out,
                      unsigned int* __restrict__ ctr2) {
    const int jt  = blockIdx.x;     // 0..4
    const int b   = blockIdx.y;     // 0..63
    const int tid = threadIdx.x;    // 0..511
    const int jl  = tid & 63;
    const int kq  = tid >> 6;       // 0..7
    const int j   = jt * 64 + jl;

    __shared__ float hr[H1_];       // 2.56 KB
    __shared__ float pt[8][64];     // 2 KB

    for (int jj = tid; jj < H1_; jj += 512)
        hr[jj] = hrow[(size_t)b * H1_ + jj];
    __syncthreads();

    // emb partial over k in [kq*80, kq*80+80)
    float a0 = 0.f, a1 = 0.f, a2 = 0.f, a3 = 0.f;
    const int kbeg = kq * (H1_ / 8);
    const float* w = W2 + (size_t)kbeg * H2_ + j;
    #pragma unroll 5
    for (int k = 0; k < H1_ / 8; k += 4) {
        const float4 hv = *(const float4*)&hr[kbeg + k];     // wave-uniform broadcast
        a0 = fmaf(hv.x, w[(size_t)(k + 0) * H2_], a0);
        a1 = fmaf(hv.y, w[(size_t)(k + 1) * H2_], a1);
        a2 = fmaf(hv.z, w[(size_t)(k + 2) * H2_], a2);
        a3 = fmaf(hv.w, w[(size_t)(k + 3) * H2_], a3);
    }
    pt[kq][jl] = (a0 + a1) + (a2 + a3);
    __syncthreads();

    if (tid < 64) {
        float e = b2[j];
        #pragma unroll
        for (int q = 0; q < 8; ++q) e += pt[q][jl];
        out[128 + (size_t)b * H2_ + j] = fmaxf(e, 0.f);
    }

    // ---- arrival count (release) ----
    __threadfence();
    __syncthreads();
    __shared__ unsigned int lastf;
    if (tid == 0) {
        unsigned int old = atomicAdd(&ctr2[b], 1u);
        lastf = (old == (unsigned)(NJT2_ - 1)) ? 1u : 0u;   // init==0 -> exact
    }
    __syncthreads();

    // ---- last block for this batch: y = emb @ W3 + b3 (one wave) ----
    if (lastf && tid < 64) {
        __threadfence();               // acquire other blocks' emb writes
        const int lane = tid;
        float s0 = 0.f, s1 = 0.f;
        #pragma unroll
        for (int i = 0; i < H2_ / 64; ++i) {
            const int jj = lane + i * 64;
            const float e = out[128 + (size_t)b * H2_ + jj];
            s0 = fmaf(e, W3[(size_t)jj * 2 + 0], s0);
            s1 = fmaf(e, W3[(size_t)jj * 2 + 1], s1);
        }
        #pragma unroll
        for (int off = 32; off >= 1; off >>= 1) {
            s0 += __shfl_xor(s0, off, 64);
            s1 += __shfl_xor(s1, off, 64);
        }
        if (lane == 0) {
            out[(size_t)b * 2 + 0] = s0 + b3[0];
            out[(size_t)b * 2 + 1] = s1 + b3[1];
        }
    }
}

extern "C" void kernel_launch(void* const* d_in, const int* in_sizes, int n_in,
                              void* d_out, int out_size, void* d_ws, size_t ws_size,
                              hipStream_t stream) {
    const float* rep  = (const float*)d_in[0];
    const int*   blen = (const int*)  d_in[1];
    const float* W1   = (const float*)d_in[2];
    const float* b1   = (const float*)d_in[3];
    const float* W2   = (const float*)d_in[4];
    const float* b2   = (const float*)d_in[5];
    const float* W3   = (const float*)d_in[6];
    const float* b3   = (const float*)d_in[7];
    float* out = (float*)d_out;

    // workspace layout (floats):
    //   part   B_*NSPLIT*D_ = 2,621,440  (10.5 MB)
    //   pooled B_*D_        =    81,920
    //   hpart  KS_*B_*H1_   =   655,360
    //   hrow   B_*H1_       =    40,960
    //   ctr1   NJT_ uints, ctr2 B_ uints
    float*        ws     = (float*)d_ws;
    float*        part   = ws;
    float*        pooled = part + (size_t)B_ * NSPLIT * D_;
    float*        hpart  = pooled + (size_t)B_ * D_;
    float*        hrow   = hpart + (size_t)KS_ * B_ * H1_;
    unsigned int* ctr1   = (unsigned int*)(hrow + (size_t)B_ * H1_);
    unsigned int* ctr2   = ctr1 + NJT_;

    pool_partial<<<dim3(NSPLIT, B_), 320, 0, stream>>>(rep, blen, part, ctr1, ctr2);
    pool_reduce <<<dim3(5, B_), 64, 0, stream>>>(part, blen, pooled);
    mlp1h       <<<dim3(NJT_, KS_), 512, 0, stream>>>(pooled, W1, b1, hpart, hrow, ctr1);
    mlp2y       <<<dim3(NJT2_, B_), 512, 0, stream>>>(hrow, W2, b2, W3, b3, out, ctr2);
}

// Round 15
// 48.430 us; speedup vs baseline: 2.4680x; 2.4680x over previous
//
#include <hip/hip_runtime.h>

// Problem constants
#define B_     64
#define L_     1024
#define D_     1280   // 320 float4
#define H1_    640
#define H2_    320
#define NSPLIT 16     // per-batch even-split stripes (16: halves part traffic vs 32)
#define KS_    16     // k-splits for mlp1
#define KC_    80     // 1280/16
#define NJT_   10     // W1 j-tiles of 64
#define NJT2_  5      // W2 j-tiles of 64

// ---------------- Kernel 1: per-batch even-split stripe partial sums ----------------
// grid (NSPLIT, B_) x 320 thr. Same streaming pattern probe-measured at the HBM
// ceiling (R8). NSPLIT=16 validated in R2. No fences, no counters (R14 lesson).
__global__ void pool_partial(const float* __restrict__ rep, const int* __restrict__ blen,
                             float* __restrict__ part) {
    const int s   = blockIdx.x;     // stripe
    const int b   = blockIdx.y;     // batch
    const int tid = threadIdx.x;    // 0..319 (float4 lane)
    const int n   = blen[b] - 2;    // valid rows (>=1)

    const int l0 = 1 + (s * n) / NSPLIT;
    const int l1 = 1 + ((s + 1) * n) / NSPLIT;

    float4 acc = make_float4(0.f, 0.f, 0.f, 0.f);
    const float4* base = (const float4*)rep + (size_t)b * L_ * (D_ / 4) + tid;
    #pragma unroll 8
    for (int l = l0; l < l1; ++l) {
        float4 v = base[(size_t)l * (D_ / 4)];
        acc.x += v.x; acc.y += v.y; acc.z += v.z; acc.w += v.w;
    }
    ((float4*)part)[((size_t)b * NSPLIT + s) * (D_ / 4) + tid] = acc;
}

// ---------------- Kernel 2: stripe reduce -> pooled (R11-proven shape) ----------------
// grid (5, B_) = 320 blocks x 64 thr: whole chip active, TLP for latency hiding.
__global__ void pool_reduce(const float* __restrict__ part, const int* __restrict__ blen,
                            float* __restrict__ pooled) {
    const int qt  = blockIdx.x;     // col quarter-tile 0..4
    const int b   = blockIdx.y;     // batch
    const int tid = threadIdx.x;    // 0..63
    const int col = qt * 64 + tid;  // float4 column 0..319

    int n = blen[b] - 2; if (n < 1) n = 1;
    const float inv = 1.0f / (float)n;
    const float4* p = (const float4*)part + (size_t)b * NSPLIT * (D_ / 4) + col;
    float4 a = make_float4(0.f, 0.f, 0.f, 0.f);
    #pragma unroll
    for (int s = 0; s < NSPLIT; ++s) {
        float4 v = p[(size_t)s * (D_ / 4)];
        a.x += v.x; a.y += v.y; a.z += v.z; a.w += v.w;
    }
    ((float4*)pooled)[(size_t)b * (D_ / 4) + col] =
        make_float4(a.x * inv, a.y * inv, a.z * inv, a.w * inv);
}

// ---------------- Kernel 3: mlp1 partials (W1 read once grid-wide; R11-proven) --------
// grid (NJT_, KS_) = 160 blocks x 512 thr (2 waves/SIMD). Thread: 8 batches x 1 col.
// hpart layout [b][ks][j]: per-batch data contiguous (40 KB) for mlp2 locality.
__global__ void mlp1_partial(const float* __restrict__ pooled, const float* __restrict__ W1,
                             float* __restrict__ hpart) {
    const int jt  = blockIdx.x;     // 0..9
    const int ks  = blockIdx.y;     // 0..15
    const int tid = threadIdx.x;    // 0..511
    const int jl  = tid & 63;
    const int b0  = (tid >> 6) * 8;
    const int k0  = ks * KC_;
    const int j0  = jt * 64;

    __shared__ float pl[B_][KC_];   // pooled k-slice (20 KB)
    for (int e = tid; e < B_ * (KC_ / 4); e += 512) {
        const int b   = e / (KC_ / 4);
        const int kk4 = e % (KC_ / 4);
        float4 v = ((const float4*)pooled)[(size_t)b * (D_ / 4) + (k0 / 4) + kk4];
        *(float4*)&pl[b][kk4 * 4] = v;
    }
    __syncthreads();

    float acc[8];
    #pragma unroll
    for (int r = 0; r < 8; ++r) acc[r] = 0.f;

    const float* w1p = W1 + (size_t)k0 * H1_ + j0 + jl;
    for (int kk = 0; kk < KC_; kk += 4) {
        const float w0 = w1p[(size_t)(kk + 0) * H1_];
        const float w1 = w1p[(size_t)(kk + 1) * H1_];
        const float w2 = w1p[(size_t)(kk + 2) * H1_];
        const float w3 = w1p[(size_t)(kk + 3) * H1_];
        #pragma unroll
        for (int r = 0; r < 8; ++r) {
            float4 pv = *(const float4*)&pl[b0 + r][kk];
            acc[r] = fmaf(pv.x, w0, acc[r]);
            acc[r] = fmaf(pv.y, w1, acc[r]);
            acc[r] = fmaf(pv.z, w2, acc[r]);
            acc[r] = fmaf(pv.w, w3, acc[r]);
        }
    }
    #pragma unroll
    for (int r = 0; r < 8; ++r)
        hpart[((size_t)(b0 + r) * KS_ + ks) * H1_ + j0 + jl] = acc[r];
}

// ---------------- Kernel 4: h-reduce + W2 j-slice -> emb (R11-proven) ----------------
// grid (NJT2_, B_) = 320 blocks x 512 thr. Batch-b hpart now one contiguous 40 KB.
__global__ void mlp2(const float* __restrict__ hpart, const float* __restrict__ b1,
                     const float* __restrict__ W2, const float* __restrict__ b2,
                     float* __restrict__ out) {
    const int jt  = blockIdx.x;     // 0..4
    const int b   = blockIdx.y;     // 0..63
    const int tid = threadIdx.x;    // 0..511
    const int jl  = tid & 63;
    const int kq  = tid >> 6;       // 0..7
    const int j   = jt * 64 + jl;

    __shared__ float hrow[H1_];     // 2.56 KB
    __shared__ float pt[8][64];     // 2 KB

    // reduce h[b][jj] over ks (contiguous per-batch chunk)
    const float* hb = hpart + (size_t)b * KS_ * H1_;
    for (int jj = tid; jj < H1_; jj += 512) {
        float s = b1[jj];
        #pragma unroll
        for (int ks = 0; ks < KS_; ++ks)
            s += hb[(size_t)ks * H1_ + jj];
        hrow[jj] = fmaxf(s, 0.f);
    }
    __syncthreads();

    // emb partial over k in [kq*80, kq*80+80)
    float a0 = 0.f, a1 = 0.f, a2 = 0.f, a3 = 0.f;
    const int kbeg = kq * (H1_ / 8);
    const float* w = W2 + (size_t)kbeg * H2_ + j;
    #pragma unroll 5
    for (int k = 0; k < H1_ / 8; k += 4) {
        const float4 hv = *(const float4*)&hrow[kbeg + k];   // wave-uniform broadcast
        a0 = fmaf(hv.x, w[(size_t)(k + 0) * H2_], a0);
        a1 = fmaf(hv.y, w[(size_t)(k + 1) * H2_], a1);
        a2 = fmaf(hv.z, w[(size_t)(k + 2) * H2_], a2);
        a3 = fmaf(hv.w, w[(size_t)(k + 3) * H2_], a3);
    }
    pt[kq][jl] = (a0 + a1) + (a2 + a3);
    __syncthreads();

    if (tid < 64) {
        float e = b2[j];
        #pragma unroll
        for (int q = 0; q < 8; ++q) e += pt[q][jl];
        out[128 + (size_t)b * H2_ + j] = fmaxf(e, 0.f);
    }
}

// ---------------- Kernel 5: y = emb @ W3 + b3 (R11-proven) ----------------
__global__ void mlp3(const float* __restrict__ out_emb, const float* __restrict__ W3,
                     const float* __restrict__ b3, float* __restrict__ out) {
    const int b    = blockIdx.x;
    const int lane = threadIdx.x;   // 0..63
    float s0 = 0.f, s1 = 0.f;
    #pragma unroll
    for (int i = 0; i < H2_ / 64; ++i) {
        const int jj = lane + i * 64;
        const float e = out_emb[128 + (size_t)b * H2_ + jj];
        s0 = fmaf(e, W3[(size_t)jj * 2 + 0], s0);
        s1 = fmaf(e, W3[(size_t)jj * 2 + 1], s1);
    }
    #pragma unroll
    for (int off = 32; off >= 1; off >>= 1) {
        s0 += __shfl_xor(s0, off, 64);
        s1 += __shfl_xor(s1, off, 64);
    }
    if (lane == 0) {
        out[(size_t)b * 2 + 0] = s0 + b3[0];
        out[(size_t)b * 2 + 1] = s1 + b3[1];
    }
}

extern "C" void kernel_launch(void* const* d_in, const int* in_sizes, int n_in,
                              void* d_out, int out_size, void* d_ws, size_t ws_size,
                              hipStream_t stream) {
    const float* rep  = (const float*)d_in[0];
    const int*   blen = (const int*)  d_in[1];
    const float* W1   = (const float*)d_in[2];
    const float* b1   = (const float*)d_in[3];
    const float* W2   = (const float*)d_in[4];
    const float* b2   = (const float*)d_in[5];
    const float* W3   = (const float*)d_in[6];
    const float* b3   = (const float*)d_in[7];
    float* out = (float*)d_out;

    // workspace layout (floats):
    //   part   B_*NSPLIT*D_ = 1,310,720  (5.24 MB)
    //   pooled B_*D_        =    81,920
    //   hpart  B_*KS_*H1_   =   655,360
    float* ws     = (float*)d_ws;
    float* part   = ws;
    float* pooled = part + (size_t)B_ * NSPLIT * D_;
    float* hpart  = pooled + (size_t)B_ * D_;

    pool_partial<<<dim3(NSPLIT, B_), 320, 0, stream>>>(rep, blen, part);
    pool_reduce <<<dim3(5, B_), 64, 0, stream>>>(part, blen, pooled);
    mlp1_partial<<<dim3(NJT_, KS_), 512, 0, stream>>>(pooled, W1, hpart);
    mlp2        <<<dim3(NJT2_, B_), 512, 0, stream>>>(hpart, b1, W2, b2, out);
    mlp3        <<<B_, 64, 0, stream>>>(out, W3, b3, out);
}